// Round 1
// baseline (103.990 us; speedup 1.0000x reference)
//
#include <hip/hip_runtime.h>
#include <hip/hip_fp16.h>
#include <math.h>

#define B_SZ 64
#define P_SZ 256
#define N_SZ 4096
#define A_ANC 0.08f
#define OMEGA_ANC 1256.6370614359172f

typedef _Float16 h2v __attribute__((ext_vector_type(2)));

__device__ __forceinline__ float fdot2f(__half2 a, __half2 b, float c) {
#if __has_builtin(__builtin_amdgcn_fdot2)
    return __builtin_amdgcn_fdot2(__builtin_bit_cast(h2v, a),
                                  __builtin_bit_cast(h2v, b), c, false);
#else
    float2 af = __half22float2(a), bf = __half22float2(b);
    return fmaf(af.x, bf.x, fmaf(af.y, bf.y, c));
#endif
}

// K1: trig tables. XP[p*N+n] = {cos(xi), sin(xi)} ; PPt[n*B+b] = {cos(phi), sin(phi)}
__global__ __launch_bounds__(256) void k_trig(const float* __restrict__ phi,
                                              const float* __restrict__ xi,
                                              __half2* __restrict__ XP,
                                              __half2* __restrict__ PPt) {
    int idx = blockIdx.x * 256 + threadIdx.x;
    const int PN = P_SZ * N_SZ;
    if (idx < PN) {
        float s, c;
        sincosf(xi[idx], &s, &c);
        XP[idx] = __floats2half2_rn(c, s);
    } else {
        int j = idx - PN;            // j = b*N + n
        float s, c;
        sincosf(phi[j], &s, &c);
        int b = j >> 12;
        int n = j & (N_SZ - 1);
        PPt[n * B_SZ + b] = __floats2half2_rn(c, s);
    }
}

// K2: m_part[nc][b][p] = sum over n-chunk of cos(phi[b,n]-xi[p,n])
// grid (16 p-tiles, 16 n-chunks), 256 threads: lane=b (0..63), g=tid>>6 strides n.
__global__ __launch_bounds__(256) void k_mpart(const __half2* __restrict__ XP,
                                               const __half2* __restrict__ PPt,
                                               float* __restrict__ m_part) {
    const int pt = blockIdx.x;          // 0..15 -> p0 = 16*pt
    const int nc = blockIdx.y;          // 0..15 -> n0 = 256*nc
    const int tid = threadIdx.x;
    const int b = tid & 63;
    const int g = tid >> 6;

    __shared__ __half2 xs[256][20];     // [n_local][p_local], pad 16->20 (80B rows, 16B aligned)
    __shared__ float red[4][64][17];

    const int p0 = pt * 16, n0 = nc * 256;
    for (int idx = tid; idx < 16 * 256; idx += 256) {
        int p_l = idx >> 8, n_l = idx & 255;
        xs[n_l][p_l] = XP[(p0 + p_l) * N_SZ + n0 + n_l];   // coalesced
    }
    __syncthreads();

    float acc[16];
#pragma unroll
    for (int j = 0; j < 16; ++j) acc[j] = 0.f;

    for (int i = 0; i < 64; ++i) {
        int n_l = 4 * i + g;
        __half2 pp = PPt[(n0 + n_l) * B_SZ + b];           // coalesced (lane=b)
        const __half2* row = &xs[n_l][0];                  // broadcast ds_read_b128 x4
#pragma unroll
        for (int j = 0; j < 16; ++j)
            acc[j] = fdot2f(row[j], pp, acc[j]);           // cosp*cosx + sinp*sinx + acc
    }

#pragma unroll
    for (int j = 0; j < 16; ++j) red[g][b][j] = acc[j];
    __syncthreads();
    if (tid < 64) {
#pragma unroll
        for (int j = 0; j < 16; ++j) {
            float s = red[0][tid][j] + red[1][tid][j] + red[2][tid][j] + red[3][tid][j];
            m_part[(nc * 64 + tid) * 256 + p0 + j] = s;
        }
    }
}

// K3: softmax (recomputed per block from m_part) + coupling + anchor.
// grid (16 b-tiles of 4, 16 n-chunks of 256), 256 threads (tid = p for softmax, n-offset for main).
__global__ __launch_bounds__(256) void k_coupling(const __half2* __restrict__ XP,
                                                  const float* __restrict__ m_part,
                                                  const float* __restrict__ phi,
                                                  const float* __restrict__ t_ptr,
                                                  float* __restrict__ out) {
    const int bt = blockIdx.x;   // 0..15
    const int nc = blockIdx.y;   // 0..15
    const int tid = threadIdx.x;
    const int wv = tid >> 6;

    __shared__ float wT[256][4];   // wT[p][b_local] -> float4 broadcast per p
    __shared__ float sred[8];

    for (int bl = 0; bl < 4; ++bl) {
        int b = bt * 4 + bl;
        float msum = 0.f;
#pragma unroll
        for (int c = 0; c < 16; ++c)
            msum += m_part[(c * 64 + b) * 256 + tid];      // coalesced
        float logit = msum * (1.0f / 4096.0f);             // BETA=1

        float v = logit;
        for (int o = 32; o > 0; o >>= 1) v = fmaxf(v, __shfl_xor(v, o));
        if ((tid & 63) == 0) sred[wv] = v;
        __syncthreads();
        float mx = fmaxf(fmaxf(sred[0], sred[1]), fmaxf(sred[2], sred[3]));
        float e = __expf(logit - mx);
        v = e;
        for (int o = 32; o > 0; o >>= 1) v += __shfl_xor(v, o);
        if ((tid & 63) == 0) sred[4 + wv] = v;
        __syncthreads();
        float s = sred[4] + sred[5] + sred[6] + sred[7];
        wT[tid][bl] = e / s;
    }
    __syncthreads();

    const int n = nc * 256 + tid;
    float aC0 = 0.f, aC1 = 0.f, aC2 = 0.f, aC3 = 0.f;
    float aS0 = 0.f, aS1 = 0.f, aS2 = 0.f, aS3 = 0.f;
    const __half2* col = XP + n;
#pragma unroll 8
    for (int p = 0; p < 256; ++p) {
        float2 cs = __half22float2(col[p * N_SZ]);         // coalesced 4B/lane
        float4 w4 = *(const float4*)(&wT[p][0]);           // ds_read_b128 broadcast
        aC0 = fmaf(w4.x, cs.x, aC0); aS0 = fmaf(w4.x, cs.y, aS0);
        aC1 = fmaf(w4.y, cs.x, aC1); aS1 = fmaf(w4.y, cs.y, aS1);
        aC2 = fmaf(w4.z, cs.x, aC2); aS2 = fmaf(w4.z, cs.y, aS2);
        aC3 = fmaf(w4.w, cs.x, aC3); aS3 = fmaf(w4.w, cs.y, aS3);
    }

    const float tv = t_ptr[0];
    const float wt = OMEGA_ANC * tv;
    float aCs[4] = {aC0, aC1, aC2, aC3};
    float aSs[4] = {aS0, aS1, aS2, aS3};
#pragma unroll
    for (int bl = 0; bl < 4; ++bl) {
        int b = bt * 4 + bl;
        float ph = phi[b * N_SZ + n];
        float s, c;
        sincosf(ph, &s, &c);
        // dphi = K*(sinphi*accC - cosphi*accS) + A*sin(omega*t - phi), K=1
        out[b * N_SZ + n] = fmaf(A_ANC, sinf(wt - ph), s * aCs[bl] - c * aSs[bl]);
    }
}

extern "C" void kernel_launch(void* const* d_in, const int* in_sizes, int n_in,
                              void* d_out, int out_size, void* d_ws, size_t ws_size,
                              hipStream_t stream) {
    const float* t   = (const float*)d_in[0];
    const float* phi = (const float*)d_in[1];
    const float* xi  = (const float*)d_in[2];
    float* out = (float*)d_out;

    char* w = (char*)d_ws;
    __half2* XP  = (__half2*)w;                                  // P*N half2 = 4 MB
    __half2* PPt = (__half2*)(w + (size_t)P_SZ * N_SZ * 4);      // N*B half2 = 1 MB
    float* m_part = (float*)(w + (size_t)P_SZ * N_SZ * 4
                               + (size_t)N_SZ * B_SZ * 4);       // 16*B*P f32 = 1 MB

    // total elements = P*N + B*N = 1310720 = 5120 * 256 exactly
    k_trig<<<5120, 256, 0, stream>>>(phi, xi, XP, PPt);
    k_mpart<<<dim3(16, 16), 256, 0, stream>>>(XP, PPt, m_part);
    k_coupling<<<dim3(16, 16), 256, 0, stream>>>(XP, m_part, phi, t, out);
}

// Round 2
// 92.480 us; speedup vs baseline: 1.1245x; 1.1245x over previous
//
#include <hip/hip_runtime.h>
#include <hip/hip_fp16.h>
#include <math.h>

#define B_SZ 64
#define P_SZ 256
#define N_SZ 4096
#define NC2 32                      // n-chunks for k_mpart (chunk = 128)
#define A_ANC 0.08f
#define OMEGA_ANC 1256.6370614359172f

typedef _Float16 h2v __attribute__((ext_vector_type(2)));

__device__ __forceinline__ float fdot2f(__half2 a, __half2 b, float c) {
#if __has_builtin(__builtin_amdgcn_fdot2)
    return __builtin_amdgcn_fdot2(__builtin_bit_cast(h2v, a),
                                  __builtin_bit_cast(h2v, b), c, false);
#else
    float2 af = __half22float2(a), bf = __half22float2(b);
    return fmaf(af.x, bf.x, fmaf(af.y, bf.y, c));
#endif
}

// K1: trig tables. XP[p*N+n] = {cos(xi), sin(xi)} ; PPt[n*B+b] = {cos(phi), sin(phi)}
__global__ __launch_bounds__(256) void k_trig(const float* __restrict__ phi,
                                              const float* __restrict__ xi,
                                              __half2* __restrict__ XP,
                                              __half2* __restrict__ PPt) {
    int idx = blockIdx.x * 256 + threadIdx.x;
    const int PN = P_SZ * N_SZ;
    if (idx < PN) {
        float s, c;
        __sincosf(xi[idx], &s, &c);         // table is half-quantized; fast path fine
        XP[idx] = __floats2half2_rn(c, s);
    } else {
        int j = idx - PN;                   // j = b*N + n
        float s, c;
        __sincosf(phi[j], &s, &c);
        int b = j >> 12;
        int n = j & (N_SZ - 1);
        PPt[n * B_SZ + b] = __floats2half2_rn(c, s);
    }
}

// K2: m_part[c][b][p] = sum over n-chunk c (128 wide) of cos(phi[b,n]-xi[p,n])
// grid (16 p-tiles, 32 n-chunks) = 512 blocks (2/CU, 8 waves/CU).
__global__ __launch_bounds__(256) void k_mpart(const __half2* __restrict__ XP,
                                               const __half2* __restrict__ PPt,
                                               float* __restrict__ m_part) {
    const int pt = blockIdx.x;          // p0 = 16*pt
    const int nc = blockIdx.y;          // n0 = 128*nc
    const int tid = threadIdx.x;
    const int b = tid & 63;
    const int g = tid >> 6;

    __shared__ __half2 xs[128][20];     // [n_local][p_local], pad 16->20 (80B rows, 16B-aligned)
    __shared__ float red[4][64][17];

    const int p0 = pt * 16, n0 = nc * 128;
    for (int idx = tid; idx < 16 * 128; idx += 256) {
        int p_l = idx >> 7, n_l = idx & 127;
        xs[n_l][p_l] = XP[(p0 + p_l) * N_SZ + n0 + n_l];   // coalesced
    }
    __syncthreads();

    float acc[16];
#pragma unroll
    for (int j = 0; j < 16; ++j) acc[j] = 0.f;

    for (int i = 0; i < 32; ++i) {
        int n_l = 4 * i + g;
        __half2 pp = PPt[(n0 + n_l) * B_SZ + b];           // coalesced (lane=b)
        const __half2* row = &xs[n_l][0];                  // broadcast ds_read_b128 x4
#pragma unroll
        for (int j = 0; j < 16; ++j)
            acc[j] = fdot2f(row[j], pp, acc[j]);
    }

#pragma unroll
    for (int j = 0; j < 16; ++j) red[g][b][j] = acc[j];
    __syncthreads();
    if (tid < 64) {
#pragma unroll
        for (int j = 0; j < 16; ++j) {
            float s = red[0][tid][j] + red[1][tid][j] + red[2][tid][j] + red[3][tid][j];
            m_part[(nc * 64 + tid) * 256 + p0 + j] = s;    // [c][b][p]
        }
    }
}

// K2.5: weights[b][p] = softmax_p( sum_c m_part[c][b][p] / N ). grid 64 x 256thr.
__global__ __launch_bounds__(256) void k_weights(const float* __restrict__ m_part,
                                                 float* __restrict__ weights) {
    const int b = blockIdx.x;
    const int tid = threadIdx.x;       // = p
    const int wv = tid >> 6;
    __shared__ float sred[8];

    float msum = 0.f;
#pragma unroll 8
    for (int c = 0; c < NC2; ++c)
        msum += m_part[(c * 64 + b) * 256 + tid];          // coalesced
    float logit = msum * (1.0f / 4096.0f);                 // BETA=1

    float v = logit;
    for (int o = 32; o > 0; o >>= 1) v = fmaxf(v, __shfl_xor(v, o));
    if ((tid & 63) == 0) sred[wv] = v;
    __syncthreads();
    float mx = fmaxf(fmaxf(sred[0], sred[1]), fmaxf(sred[2], sred[3]));
    float e = __expf(logit - mx);
    v = e;
    for (int o = 32; o > 0; o >>= 1) v += __shfl_xor(v, o);
    if ((tid & 63) == 0) sred[4 + wv] = v;
    __syncthreads();
    float s = sred[4] + sred[5] + sred[6] + sred[7];
    weights[b * 256 + tid] = e / s;
}

// K3: coupling + anchor. grid (16 b-tiles of 4, 64 n-chunks of 64) = 1024 blocks.
// Each wave owns one b (wave-uniform weight), lane = n offset.
__global__ __launch_bounds__(256) void k_coupling(const __half2* __restrict__ XP,
                                                  const float* __restrict__ weights,
                                                  const float* __restrict__ phi,
                                                  const float* __restrict__ t_ptr,
                                                  float* __restrict__ out) {
    const int bt = blockIdx.x;   // 0..15
    const int nc = blockIdx.y;   // 0..63
    const int tid = threadIdx.x;
    const int b_l = tid >> 6;    // wave id = local b
    const int lane = tid & 63;

    __shared__ float wsh[4][256];
    for (int idx = tid; idx < 4 * 256; idx += 256) {
        int bb = idx >> 8, p = idx & 255;
        wsh[bb][p] = weights[(bt * 4 + bb) * 256 + p];     // coalesced
    }
    __syncthreads();

    const int n = nc * 64 + lane;
    const __half2* col = XP + n;
    float aC = 0.f, aS = 0.f;
#pragma unroll 8
    for (int p = 0; p < 256; ++p) {
        float2 cs = __half22float2(col[p * N_SZ]);         // 4B/lane coalesced
        float w = wsh[b_l][p];                             // wave-uniform -> LDS broadcast
        aC = fmaf(w, cs.x, aC);
        aS = fmaf(w, cs.y, aS);
    }

    const int b = bt * 4 + b_l;
    float ph = phi[b * N_SZ + n];
    float s, c;
    sincosf(ph, &s, &c);                                   // accurate libm in epilogue
    float wt = OMEGA_ANC * t_ptr[0];
    // dphi = sinphi*aC - cosphi*aS + A*sin(omega*t - phi)
    out[b * N_SZ + n] = fmaf(A_ANC, sinf(wt - ph), s * aC - c * aS);
}

extern "C" void kernel_launch(void* const* d_in, const int* in_sizes, int n_in,
                              void* d_out, int out_size, void* d_ws, size_t ws_size,
                              hipStream_t stream) {
    const float* t   = (const float*)d_in[0];
    const float* phi = (const float*)d_in[1];
    const float* xi  = (const float*)d_in[2];
    float* out = (float*)d_out;

    char* w = (char*)d_ws;
    __half2* XP  = (__half2*)w;                                  // P*N half2  = 4 MB
    __half2* PPt = (__half2*)(w + (size_t)P_SZ * N_SZ * 4);      // N*B half2  = 1 MB
    float* m_part = (float*)(w + 5u * 1024 * 1024);              // 32*64*256 f32 = 8 MB
    float* weights = (float*)(w + 13u * 1024 * 1024);            // 64*256 f32 = 64 KB

    // total trig elements = P*N + B*N = 1310720 = 5120 * 256 exactly
    k_trig<<<5120, 256, 0, stream>>>(phi, xi, XP, PPt);
    k_mpart<<<dim3(16, NC2), 256, 0, stream>>>(XP, PPt, m_part);
    k_weights<<<64, 256, 0, stream>>>(m_part, weights);
    k_coupling<<<dim3(16, 64), 256, 0, stream>>>(XP, weights, phi, t, out);
}